// Round 4
// baseline (14275.102 us; speedup 1.0000x reference)
//
#include <hip/hip_runtime.h>
#include <hip/hip_cooperative_groups.h>
#include <math.h>

namespace cg = cooperative_groups;

#define B_    16
#define L_    2048
#define LM1   2047
#define D_    1024
#define H_    512
#define TBLK  64
#define NBLK  32   // ceil(2047/64)
#define NWG   256

// ---------------------------------------------------------------------------
// K[r][n] = sum_d x[b*L+t][d] * Wcat[n][d],  r = b*LM1 + t, n in [0,1024)
// grid (512, 16), block 256
// ---------------------------------------------------------------------------
__global__ void k_proj(const float* __restrict__ x, const float* __restrict__ Wsem,
                       const float* __restrict__ Wepi, float* __restrict__ K)
{
    __shared__ float As[16][68];
    __shared__ float Bs[16][68];
    const int tid = threadIdx.x;
    const int tx = tid & 15, ty = tid >> 4;
    const int r0 = blockIdx.x * 64;
    const int n0 = blockIdx.y * 64;
    const int lr  = tid >> 2;
    const int lk4 = (tid & 3) << 2;
    const int rowg = r0 + lr;
    const bool rok = rowg < B_ * LM1;
    const int rowc = rok ? rowg : 0;
    const int bb = rowc / LM1;
    const int tt = rowc - bb * LM1;
    const float* xrow = x + ((size_t)bb * L_ + tt) * D_;
    const int nW = n0 + lr;
    const float* wrow = (nW < H_) ? (Wsem + (size_t)nW * D_)
                                  : (Wepi + (size_t)(nW - H_) * D_);
    float acc[4][4];
#pragma unroll
    for (int i = 0; i < 4; ++i)
#pragma unroll
        for (int j = 0; j < 4; ++j) acc[i][j] = 0.f;

    for (int kk = 0; kk < D_; kk += 16) {
        const float4 av = rok ? *(const float4*)(xrow + kk + lk4) : make_float4(0.f,0.f,0.f,0.f);
        const float4 bv = *(const float4*)(wrow + kk + lk4);
        As[lk4+0][lr] = av.x; As[lk4+1][lr] = av.y; As[lk4+2][lr] = av.z; As[lk4+3][lr] = av.w;
        Bs[lk4+0][lr] = bv.x; Bs[lk4+1][lr] = bv.y; Bs[lk4+2][lr] = bv.z; Bs[lk4+3][lr] = bv.w;
        __syncthreads();
#pragma unroll
        for (int k = 0; k < 16; ++k) {
            const float4 a4 = *(const float4*)&As[k][ty << 2];
            const float4 b4 = *(const float4*)&Bs[k][tx << 2];
            const float aa[4] = {a4.x, a4.y, a4.z, a4.w};
            const float bbv[4] = {b4.x, b4.y, b4.z, b4.w};
#pragma unroll
            for (int i = 0; i < 4; ++i)
#pragma unroll
                for (int j = 0; j < 4; ++j)
                    acc[i][j] = fmaf(aa[i], bbv[j], acc[i][j]);
        }
        __syncthreads();
    }
#pragma unroll
    for (int i = 0; i < 4; ++i) {
        const int r = r0 + (ty << 2) + i;
        if (r < B_ * LM1)
            *(float4*)(K + (size_t)r * D_ + n0 + (tx << 2)) =
                make_float4(acc[i][0], acc[i][1], acc[i][2], acc[i][3]);
    }
}

// ---------------------------------------------------------------------------
// squared norms + reciprocal norms per (b, m, t).  grid B_*LM1, block 256
// ---------------------------------------------------------------------------
__global__ void k_norms(const float* __restrict__ K, float* __restrict__ nk2,
                        float* __restrict__ rn)
{
    const int r = blockIdx.x;               // b*LM1 + t
    const int tid = threadIdx.x;            // 256
    const float4 v = *(const float4*)(K + (size_t)r * D_ + (tid << 2));
    float s = v.x*v.x + v.y*v.y + v.z*v.z + v.w*v.w;
#pragma unroll
    for (int o = 32; o; o >>= 1) s += __shfl_xor(s, o);
    __shared__ float part[4];
    const int wid = tid >> 6, lane = tid & 63;
    if (lane == 0) part[wid] = s;
    __syncthreads();
    if (tid == 0) {
        const int b = r / LM1, t = r - b * LM1;
        const float s0 = part[0] + part[1];
        const float s1 = part[2] + part[3];
        nk2[(size_t)(b*2+0)*LM1 + t] = s0;
        nk2[(size_t)(b*2+1)*LM1 + t] = s1;
        rn [(size_t)(b*2+0)*LM1 + t] = 1.f / fmaxf(sqrtf(s0), 1e-12f);
        rn [(size_t)(b*2+1)*LM1 + t] = 1.f / fmaxf(sqrtf(s1), 1e-12f);
    }
}

// ---------------------------------------------------------------------------
// Gram (all blocks, hoisted): G[bm][blk][t][d] = kn_t . kn_{t+d}   (shifted layout)
// grid (NBLK, B_*2), block 256
// ---------------------------------------------------------------------------
__global__ void k_gram(const float* __restrict__ K, const float* __restrict__ rn,
                       float* __restrict__ G)
{
    const int blk = blockIdx.x;
    const int bm  = blockIdx.y;
    const int b = bm >> 1, m = bm & 1;
    const int t0 = blk * TBLK;
    const int Tb = (LM1 - t0 < TBLK) ? (LM1 - t0) : TBLK;
    __shared__ float As[16][68];
    const int tid = threadIdx.x;
    const int tx = tid & 15, ty = tid >> 4;
    const int lr = tid >> 2, lk4 = (tid & 3) << 2;
    const float* Abase = K + ((size_t)(b * LM1 + t0)) * D_ + m * H_;
    float acc[4][4];
#pragma unroll
    for (int i = 0; i < 4; ++i)
#pragma unroll
        for (int j = 0; j < 4; ++j) acc[i][j] = 0.f;

    for (int kk = 0; kk < H_; kk += 16) {
        const float4 av = (lr < Tb) ? *(const float4*)(Abase + (size_t)lr * D_ + kk + lk4)
                                    : make_float4(0.f,0.f,0.f,0.f);
        As[lk4+0][lr] = av.x; As[lk4+1][lr] = av.y; As[lk4+2][lr] = av.z; As[lk4+3][lr] = av.w;
        __syncthreads();
#pragma unroll
        for (int k = 0; k < 16; ++k) {
            const float4 a4 = *(const float4*)&As[k][ty << 2];
            const float4 b4 = *(const float4*)&As[k][tx << 2];
            const float aa[4] = {a4.x, a4.y, a4.z, a4.w};
            const float bbv[4] = {b4.x, b4.y, b4.z, b4.w};
#pragma unroll
            for (int i = 0; i < 4; ++i)
#pragma unroll
                for (int j = 0; j < 4; ++j)
                    acc[i][j] = fmaf(aa[i], bbv[j], acc[i][j]);
        }
        __syncthreads();
    }
    const float* rnb = rn + (size_t)bm * LM1 + t0;
    float* Gout = G + ((size_t)bm * NBLK + blk) * (TBLK * TBLK);
#pragma unroll
    for (int i = 0; i < 4; ++i) {
        const int t = (ty << 2) + i;
        const float rt = (t < Tb) ? rnb[t] : 0.f;
#pragma unroll
        for (int j = 0; j < 4; ++j) {
            const int s = (tx << 2) + j;
            const int d = s - t;
            if (d >= 0) {
                const float val = (t < Tb && s < Tb) ? rt * rnb[s] * acc[i][j] : 0.f;
                Gout[(size_t)t * TBLK + d] = val;
            }
        }
    }
}

// ---------------------------------------------------------------------------
// Fused scan, 1024-thread blocks (16 waves), 1 WG/CU, VGPR cap 128.
// Phase B: one m per thread -> p[64] state fits in registers (round-2/3 had
// both m per thread = 128 floats -> scratch spill -> 8.8 ms latency-bound).
// ---------------------------------------------------------------------------
__global__ void __launch_bounds__(1024, 4) k_scan(
    const float* __restrict__ K, const float* __restrict__ rn,
    const float* __restrict__ nk2, const float* __restrict__ G,
    float* __restrict__ Mm, float* __restrict__ Vext, float* __restrict__ AU,
    float omA)
{
    cg::grid_group grid = cg::this_grid();
    const int wg  = blockIdx.x;
    const int tid = threadIdx.x;
    __shared__ float sh[8704];     // A: 2x[32][68]=4352 | B: Gsh 8192 | C: 4x2176=8704
    __shared__ float part[32];

    // zero M
    {
        float4* M4 = (float4*)Mm;
        for (int i = wg * 1024 + tid; i < (B_*2*H_*H_) / 4; i += NWG * 1024)
            M4[i] = make_float4(0.f, 0.f, 0.f, 0.f);
    }
    grid.sync();

    for (int blk = 0; blk < NBLK; ++blk) {
        const int t0 = blk * TBLK;
        const int Tb = (LM1 - t0 < TBLK) ? (LM1 - t0) : TBLK;

        // ---------------- Phase A : Vext = rn ⊙ (K_blk @ M^T) ----------------
        // one 64t x 64n tile per WG, K=512 sequential in chunks of 32.
        {
            float* As = sh;              // [32][68]
            float* Bs = sh + 2176;       // [32][68]
            const int bm = wg >> 3, n0 = (wg & 7) << 6;
            const int b = bm >> 1, m = bm & 1;
            const int tx = tid & 31, ty = tid >> 5;          // 32x32
            const int sr = tid >> 4;                          // stage row 0..63
            const int sc = (tid & 15) << 1;                   // stage col 0..30 (x2)
            const float* Abase = K + ((size_t)(b * LM1 + t0)) * D_ + m * H_;
            const float* Bbase = Mm + (size_t)bm * H_ * H_;
            float acc[2][2];
            acc[0][0] = acc[0][1] = acc[1][0] = acc[1][1] = 0.f;

            for (int kk = 0; kk < H_; kk += 32) {
                float2 av = make_float2(0.f, 0.f);
                if (sr < Tb) av = *(const float2*)(Abase + (size_t)sr * D_ + kk + sc);
                const float2 bv = *(const float2*)(Bbase + (size_t)(n0 + sr) * H_ + kk + sc);
                As[(sc+0)*68 + sr] = av.x; As[(sc+1)*68 + sr] = av.y;
                Bs[(sc+0)*68 + sr] = bv.x; Bs[(sc+1)*68 + sr] = bv.y;
                __syncthreads();
#pragma unroll
                for (int k = 0; k < 32; ++k) {
                    const float2 a2 = *(const float2*)&As[k*68 + (ty << 1)];
                    const float2 b2 = *(const float2*)&Bs[k*68 + (tx << 1)];
                    acc[0][0] = fmaf(a2.x, b2.x, acc[0][0]);
                    acc[0][1] = fmaf(a2.x, b2.y, acc[0][1]);
                    acc[1][0] = fmaf(a2.y, b2.x, acc[1][0]);
                    acc[1][1] = fmaf(a2.y, b2.y, acc[1][1]);
                }
                __syncthreads();
            }
            const float* rnb = rn + (size_t)bm * LM1 + t0;
#pragma unroll
            for (int ii = 0; ii < 2; ++ii) {
                const int t = (ty << 1) + ii;
                if (t < Tb) {
                    const float rv = rnb[t];
                    *(float2*)(Vext + ((size_t)bm * TBLK + t) * H_ + n0 + (tx << 1)) =
                        make_float2(rv * acc[ii][0], rv * acc[ii][1]);
                }
            }
        }
        grid.sync();

        // ---------------- Phase B (seq): thread = (m, j) ----------------
        if (wg < B_) {
            const int b = wg;
            const int m = tid >> 9;            // 0: sem, 1: epi
            const int wid = tid >> 6, lane = tid & 63;
            {
                // Gsh: m0 at sh[0..4096), m1 at sh[4096..8192)
                const float4* s0 = (const float4*)(G + ((size_t)(b*2+0) * NBLK + blk) * (TBLK*TBLK));
                const float4* s1 = (const float4*)(G + ((size_t)(b*2+1) * NBLK + blk) * (TBLK*TBLK));
                float4* dst = (float4*)sh;
                dst[tid] = (tid < 1024) ? s0[tid] : s0[tid];   // tid<1024 always
                dst[tid + 1024] = s1[tid];
            }
            float p[TBLK];
#pragma unroll
            for (int i = 0; i < TBLK; ++i) p[i] = 0.f;
            __syncthreads();

            // m*H_ + j == tid  (since D_ = 2*H_)
            const float* Kb = K + ((size_t)(b * LM1 + t0)) * D_ + tid;
            const float* Vb = Vext + ((size_t)(b*2) * TBLK) * H_ + (m ? (size_t)TBLK * H_ : 0) + (tid & 511);
            float* AUp = AU + ((size_t)(b*2) * TBLK) * H_ + (m ? (size_t)TBLK * H_ : 0) + (tid & 511);
            const float* q = nk2 + (size_t)(b*2 + m) * LM1 + t0;

            float kc = Kb[0], vc = Vb[0], nc = q[0];

            for (int t = 0; t < Tb; ++t) {
                const float u = kc - vc - p[0];
                float kn = 0.f, vn = 0.f, nn = 0.f;
                if (t + 1 < Tb) {
                    kn = Kb[(size_t)(t+1) * D_];
                    vn = Vb[(t+1) * H_];
                    nn = q[t+1];
                }
                float s = u * u;
#pragma unroll
                for (int o = 32; o; o >>= 1) s += __shfl_xor(s, o);
                float* pp = &part[(t & 1) << 4];
                if (lane == 0) pp[wid] = s;
                __syncthreads();
                float Ns = 0.f, Ne = 0.f;
#pragma unroll
                for (int i = 0; i < 8; ++i) { Ns += pp[i]; Ne += pp[i + 8]; }
                // fire needs 0.49*nk2 of OWN m; nc holds own-m nk2. But gate is
                // (err_s >= ref_s) || (err_e >= ref_e): compare per-m then OR.
                // part sums: Ns = err_s^2, Ne = err_e^2. Need both m's nk2:
                // each thread knows own nc only -> stash nk2 per m in part[30/31].
                if (tid == 0)   part[30 + 0] = nc;    // overwritten below properly
                // (see note: we instead load both nk2 from global each step)
                const float n2s = q ? 0.f : 0.f;      // placeholder, real gate below
                (void)n2s;
                const float nk2_s = nk2[(size_t)(b*2+0) * LM1 + t0 + t];
                const float nk2_e = nk2[(size_t)(b*2+1) * LM1 + t0 + t];
                const bool fire = (Ns >= 0.49f * nk2_s) || (Ne >= 0.49f * nk2_e);
                const float w = (float)(t0 + t + 1) * (1.0f / (float)L_);
                const float scale = m ? (omA * w) : omA;
                const float vv = fire ? scale * u : 0.f;
                AUp[(size_t)t * H_] = vv;
                const float* g = sh + ((m << 6) + t) * TBLK;
                if (fire) {
#pragma unroll
                    for (int qq = 0; qq < 16; ++qq) {
                        const float4 a = ((const float4*)g)[qq];
                        const int d0 = qq << 2;
                        if (qq > 0) p[d0-1] = fmaf(a.x, vv, p[d0]);
                        p[d0+0] = fmaf(a.y, vv, p[d0+1]);
                        p[d0+1] = fmaf(a.z, vv, p[d0+2]);
                        p[d0+2] = fmaf(a.w, vv, p[d0+3]);
                    }
                } else {
#pragma unroll
                    for (int d = 1; d < TBLK; ++d) p[d-1] = p[d];
                }
                p[TBLK-1] = 0.f;
                kc = kn; vc = vn; nc = nn;
            }
        }
        grid.sync();

        // ---------------- Phase C : M += (a∘U)^T @ (rn ⊙ K_blk) ----------------
        // 4 teams of 256 per WG, 2 rounds -> 2048 tile-tasks
        {
            const int sub = tid >> 8, t256 = tid & 255;
            float* As = sh + sub * 2176;
            float* Bs = As + 1088;
            const int tx = t256 & 15, ty = t256 >> 4;
            const int lk = t256 >> 4, lc4 = (t256 & 15) << 2;
#pragma unroll
            for (int rq = 0; rq < 2; ++rq) {
                const int task = rq * 1024 + wg * 4 + sub;    // 0..2047
                const int bm = task >> 6;
                const int i0 = ((task >> 3) & 7) << 6;
                const int j0 = (task & 7) << 6;
                const int b = bm >> 1, m = bm & 1;
                float acc[4][4];
#pragma unroll
                for (int i = 0; i < 4; ++i)
#pragma unroll
                    for (int j = 0; j < 4; ++j) acc[i][j] = 0.f;

                for (int kk = 0; kk < TBLK; kk += 16) {
                    const int kt = kk + lk;
                    const bool ok = kt < Tb;
                    float4 av = ok ? *(const float4*)(AU + ((size_t)bm * TBLK + kt) * H_ + i0 + lc4)
                                   : make_float4(0.f,0.f,0.f,0.f);
                    const float rv = ok ? rn[(size_t)bm * LM1 + t0 + kt] : 0.f;
                    float4 bv = ok ? *(const float4*)(K + ((size_t)(b * LM1 + t0 + kt)) * D_ + m * H_ + j0 + lc4)
                                   : make_float4(0.f,0.f,0.f,0.f);
                    bv.x *= rv; bv.y *= rv; bv.z *= rv; bv.w *= rv;
                    *(float4*)&As[lk*68 + lc4] = av;
                    *(float4*)&Bs[lk*68 + lc4] = bv;
                    __syncthreads();
#pragma unroll
                    for (int k = 0; k < 16; ++k) {
                        const float4 a4 = *(const float4*)&As[k*68 + (ty << 2)];
                        const float4 b4 = *(const float4*)&Bs[k*68 + (tx << 2)];
                        const float aa[4] = {a4.x, a4.y, a4.z, a4.w};
                        const float bbv[4] = {b4.x, b4.y, b4.z, b4.w};
#pragma unroll
                        for (int i = 0; i < 4; ++i)
#pragma unroll
                            for (int j = 0; j < 4; ++j)
                                acc[i][j] = fmaf(aa[i], bbv[j], acc[i][j]);
                    }
                    __syncthreads();
                }
#pragma unroll
                for (int i = 0; i < 4; ++i) {
                    float4* pt = (float4*)(Mm + ((size_t)bm * H_ + i0 + (ty << 2) + i) * H_ + j0 + (tx << 2));
                    float4 old = *pt;
                    old.x += acc[i][0]; old.y += acc[i][1]; old.z += acc[i][2]; old.w += acc[i][3];
                    *pt = old;
                }
            }
        }
        grid.sync();
    }
}

// ---------------------------------------------------------------------------
// query path: qn (normalized projections) + gnull.  grid B_, block 1024
// ---------------------------------------------------------------------------
__global__ void __launch_bounds__(1024) k_q(
    const float* __restrict__ x, const float* __restrict__ Wsem,
    const float* __restrict__ Wepi, const float* __restrict__ nw,
    const float* __restrict__ nb, float* __restrict__ qn, float* __restrict__ gnull)
{
    const int b = blockIdx.x, tid = threadIdx.x;
    __shared__ float qsh[D_];
    __shared__ float red[16];
    qsh[tid] = x[((size_t)b * L_ + (L_ - 1)) * D_ + tid];
    __syncthreads();
    const float* wrow = (tid < H_) ? (Wsem + (size_t)tid * D_)
                                   : (Wepi + (size_t)(tid - H_) * D_);
    float s = 0.f;
    for (int d = 0; d < D_; d += 4) {
        const float4 w4 = *(const float4*)(wrow + d);
        s += qsh[d]*w4.x + qsh[d+1]*w4.y + qsh[d+2]*w4.z + qsh[d+3]*w4.w;
    }
    float sq = s * s;
#pragma unroll
    for (int o = 32; o; o >>= 1) sq += __shfl_xor(sq, o);
    const int wid = tid >> 6, lane = tid & 63;
    if (lane == 0) red[wid] = sq;
    __syncthreads();
    float n2s = 0.f, n2e = 0.f;
#pragma unroll
    for (int i = 0; i < 8; ++i) { n2s += red[i]; n2e += red[i + 8]; }
    const float rns = 1.f / fmaxf(sqrtf(n2s), 1e-12f);
    const float rne = 1.f / fmaxf(sqrtf(n2e), 1e-12f);
    qn[(size_t)b * D_ + tid] = s * ((tid < H_) ? rns : rne);
    if (wid == 0) {
        float g = 0.f;
        for (int d = lane * 4; d < D_; d += 256) {
            const float4 w4 = *(const float4*)(nw + d);
            g += qsh[d]*w4.x + qsh[d+1]*w4.y + qsh[d+2]*w4.z + qsh[d+3]*w4.w;
        }
#pragma unroll
        for (int o = 32; o; o >>= 1) g += __shfl_xor(g, o);
        if (lane == 0) gnull[b] = 1.f / (1.f + expf(-(g + nb[0])));
    }
}

// ---------------------------------------------------------------------------
// rg[b][n] = gnull[b] * sum_j M[b][m][i][j] qn[b][m*512+j]   grid (16,256), block 256
// ---------------------------------------------------------------------------
__global__ void k_rmv(const float* __restrict__ M, const float* __restrict__ qn,
                      const float* __restrict__ gnull, float* __restrict__ rg)
{
    const int b = blockIdx.x;
    const int n = blockIdx.y * 4 + (threadIdx.x >> 6);
    const int lane = threadIdx.x & 63;
    const int m = n >> 9, i = n & 511;
    const float* Mr = M + ((size_t)(b*2+m) * H_ + i) * H_;
    const float* qv = qn + (size_t)b * D_ + m * H_;
    float s = 0.f;
#pragma unroll
    for (int it = 0; it < 2; ++it) {
        const int j = lane * 4 + it * 256;
        const float4 m4 = *(const float4*)(Mr + j);
        const float4 q4 = *(const float4*)(qv + j);
        s += m4.x*q4.x + m4.y*q4.y + m4.z*q4.z + m4.w*q4.w;
    }
#pragma unroll
    for (int o = 32; o; o >>= 1) s += __shfl_xor(s, o);
    if (lane == 0) rg[(size_t)b * D_ + n] = gnull[b] * s;
}

// ---------------------------------------------------------------------------
// out[b][o] = sum_d rg[b][d] * outw[o][d] + outb[o]        grid (16,256), block 256
// ---------------------------------------------------------------------------
__global__ void k_out(const float* __restrict__ rg, const float* __restrict__ outw,
                      const float* __restrict__ outb, float* __restrict__ out)
{
    const int b = blockIdx.x;
    const int o = blockIdx.y * 4 + (threadIdx.x >> 6);
    const int lane = threadIdx.x & 63;
    const float* wr = outw + (size_t)o * D_;
    const float* rv = rg + (size_t)b * D_;
    float s = 0.f;
#pragma unroll
    for (int it = 0; it < 4; ++it) {
        const int j = lane * 4 + it * 256;
        const float4 w4 = *(const float4*)(wr + j);
        const float4 r4 = *(const float4*)(rv + j);
        s += w4.x*r4.x + w4.y*r4.y + w4.z*r4.z + w4.w*r4.w;
    }
#pragma unroll
    for (int o2 = 32; o2; o2 >>= 1) s += __shfl_xor(s, o2);
    if (lane == 0) out[(size_t)b * D_ + o] = s + outb[o];
}

// ---------------------------------------------------------------------------
extern "C" void kernel_launch(void* const* d_in, const int* in_sizes, int n_in,
                              void* d_out, int out_size, void* d_ws, size_t ws_size,
                              hipStream_t stream)
{
    (void)in_sizes; (void)n_in; (void)out_size;
    const float* x     = (const float*)d_in[0];
    const float* Wsem  = (const float*)d_in[1];
    const float* Wepi  = (const float*)d_in[2];
    const float* nullw = (const float*)d_in[3];
    const float* nullb = (const float*)d_in[4];
    const float* outw  = (const float*)d_in[5];
    const float* outb  = (const float*)d_in[6];
    float* out = (float*)d_out;

    float* ws = (float*)d_ws;
    size_t off = 0;
    float* K     = ws + off; off += (size_t)B_ * LM1 * D_;
    float* nk2   = ws + off; off += (size_t)B_ * 2 * LM1;
    float* rn    = ws + off; off += (size_t)B_ * 2 * LM1;
    float* Mm    = ws + off; off += (size_t)B_ * 2 * H_ * H_;
    float* Vext  = ws + off; off += (size_t)B_ * 2 * TBLK * H_;
    float* G     = ws + off; off += (size_t)B_ * 2 * NBLK * TBLK * TBLK;
    float* AU    = ws + off; off += (size_t)B_ * 2 * TBLK * H_;
    float* qn    = ws + off; off += (size_t)B_ * D_;
    float* gnull = ws + off; off += (size_t)B_;
    float* rg    = ws + off; off += (size_t)B_ * D_;
    if (ws_size < off * sizeof(float)) return;   // insufficient scratch -> fail loudly

    float omA = (float)(1.0 - pow(0.95, 96.0 / 2048.0));

    k_proj <<<dim3(512, 16), 256, 0, stream>>>(x, Wsem, Wepi, K);
    k_norms<<<dim3(B_ * LM1), 256, 0, stream>>>(K, nk2, rn);
    k_gram <<<dim3(NBLK, B_ * 2), 256, 0, stream>>>(K, rn, G);

    {
        void* args[] = { (void*)&K, (void*)&rn, (void*)&nk2, (void*)&G,
                         (void*)&Mm, (void*)&Vext, (void*)&AU, (void*)&omA };
        hipLaunchCooperativeKernel((void*)k_scan, dim3(NWG), dim3(1024), args, 0, stream);
    }

    k_q  <<<dim3(B_), 1024, 0, stream>>>(x, Wsem, Wepi, nullw, nullb, qn, gnull);
    k_rmv<<<dim3(16, 256), 256, 0, stream>>>(Mm, qn, gnull, rg);
    k_out<<<dim3(16, 256), 256, 0, stream>>>(rg, outw, outb, out);
}

// Round 5
// 9992.363 us; speedup vs baseline: 1.4286x; 1.4286x over previous
//
#include <hip/hip_runtime.h>
#include <hip/hip_cooperative_groups.h>
#include <math.h>

namespace cg = cooperative_groups;

#define B_    16
#define L_    2048
#define LM1   2047
#define D_    1024
#define H_    512
#define TBLK  64
#define NBLK  32   // ceil(2047/64)
#define NWG   256

// ---------------------------------------------------------------------------
// K[r][n] = sum_d x[b*L+t][d] * Wcat[n][d],  r = b*LM1 + t, n in [0,1024)
// grid (512, 16), block 256
// ---------------------------------------------------------------------------
__global__ void k_proj(const float* __restrict__ x, const float* __restrict__ Wsem,
                       const float* __restrict__ Wepi, float* __restrict__ K)
{
    __shared__ float As[16][68];
    __shared__ float Bs[16][68];
    const int tid = threadIdx.x;
    const int tx = tid & 15, ty = tid >> 4;
    const int r0 = blockIdx.x * 64;
    const int n0 = blockIdx.y * 64;
    const int lr  = tid >> 2;
    const int lk4 = (tid & 3) << 2;
    const int rowg = r0 + lr;
    const bool rok = rowg < B_ * LM1;
    const int rowc = rok ? rowg : 0;
    const int bb = rowc / LM1;
    const int tt = rowc - bb * LM1;
    const float* xrow = x + ((size_t)bb * L_ + tt) * D_;
    const int nW = n0 + lr;
    const float* wrow = (nW < H_) ? (Wsem + (size_t)nW * D_)
                                  : (Wepi + (size_t)(nW - H_) * D_);
    float acc[4][4];
#pragma unroll
    for (int i = 0; i < 4; ++i)
#pragma unroll
        for (int j = 0; j < 4; ++j) acc[i][j] = 0.f;

    for (int kk = 0; kk < D_; kk += 16) {
        const float4 av = rok ? *(const float4*)(xrow + kk + lk4) : make_float4(0.f,0.f,0.f,0.f);
        const float4 bv = *(const float4*)(wrow + kk + lk4);
        As[lk4+0][lr] = av.x; As[lk4+1][lr] = av.y; As[lk4+2][lr] = av.z; As[lk4+3][lr] = av.w;
        Bs[lk4+0][lr] = bv.x; Bs[lk4+1][lr] = bv.y; Bs[lk4+2][lr] = bv.z; Bs[lk4+3][lr] = bv.w;
        __syncthreads();
#pragma unroll
        for (int k = 0; k < 16; ++k) {
            const float4 a4 = *(const float4*)&As[k][ty << 2];
            const float4 b4 = *(const float4*)&Bs[k][tx << 2];
            const float aa[4] = {a4.x, a4.y, a4.z, a4.w};
            const float bbv[4] = {b4.x, b4.y, b4.z, b4.w};
#pragma unroll
            for (int i = 0; i < 4; ++i)
#pragma unroll
                for (int j = 0; j < 4; ++j)
                    acc[i][j] = fmaf(aa[i], bbv[j], acc[i][j]);
        }
        __syncthreads();
    }
#pragma unroll
    for (int i = 0; i < 4; ++i) {
        const int r = r0 + (ty << 2) + i;
        if (r < B_ * LM1)
            *(float4*)(K + (size_t)r * D_ + n0 + (tx << 2)) =
                make_float4(acc[i][0], acc[i][1], acc[i][2], acc[i][3]);
    }
}

// ---------------------------------------------------------------------------
// squared norms + reciprocal norms per (b, m, t).  grid B_*LM1, block 256
// ---------------------------------------------------------------------------
__global__ void k_norms(const float* __restrict__ K, float* __restrict__ nk2,
                        float* __restrict__ rn)
{
    const int r = blockIdx.x;               // b*LM1 + t
    const int tid = threadIdx.x;            // 256
    const float4 v = *(const float4*)(K + (size_t)r * D_ + (tid << 2));
    float s = v.x*v.x + v.y*v.y + v.z*v.z + v.w*v.w;
#pragma unroll
    for (int o = 32; o; o >>= 1) s += __shfl_xor(s, o);
    __shared__ float part[4];
    const int wid = tid >> 6, lane = tid & 63;
    if (lane == 0) part[wid] = s;
    __syncthreads();
    if (tid == 0) {
        const int b = r / LM1, t = r - b * LM1;
        const float s0 = part[0] + part[1];
        const float s1 = part[2] + part[3];
        nk2[(size_t)(b*2+0)*LM1 + t] = s0;
        nk2[(size_t)(b*2+1)*LM1 + t] = s1;
        rn [(size_t)(b*2+0)*LM1 + t] = 1.f / fmaxf(sqrtf(s0), 1e-12f);
        rn [(size_t)(b*2+1)*LM1 + t] = 1.f / fmaxf(sqrtf(s1), 1e-12f);
    }
}

// ---------------------------------------------------------------------------
// Gram (all blocks, hoisted): G[bm][blk][t][d] = kn_t . kn_{t+d}   (shifted layout)
// grid (NBLK, B_*2), block 256
// ---------------------------------------------------------------------------
__global__ void k_gram(const float* __restrict__ K, const float* __restrict__ rn,
                       float* __restrict__ G)
{
    const int blk = blockIdx.x;
    const int bm  = blockIdx.y;
    const int b = bm >> 1, m = bm & 1;
    const int t0 = blk * TBLK;
    const int Tb = (LM1 - t0 < TBLK) ? (LM1 - t0) : TBLK;
    __shared__ float As[16][68];
    const int tid = threadIdx.x;
    const int tx = tid & 15, ty = tid >> 4;
    const int lr = tid >> 2, lk4 = (tid & 3) << 2;
    const float* Abase = K + ((size_t)(b * LM1 + t0)) * D_ + m * H_;
    float acc[4][4];
#pragma unroll
    for (int i = 0; i < 4; ++i)
#pragma unroll
        for (int j = 0; j < 4; ++j) acc[i][j] = 0.f;

    for (int kk = 0; kk < H_; kk += 16) {
        const float4 av = (lr < Tb) ? *(const float4*)(Abase + (size_t)lr * D_ + kk + lk4)
                                    : make_float4(0.f,0.f,0.f,0.f);
        As[lk4+0][lr] = av.x; As[lk4+1][lr] = av.y; As[lk4+2][lr] = av.z; As[lk4+3][lr] = av.w;
        __syncthreads();
#pragma unroll
        for (int k = 0; k < 16; ++k) {
            const float4 a4 = *(const float4*)&As[k][ty << 2];
            const float4 b4 = *(const float4*)&As[k][tx << 2];
            const float aa[4] = {a4.x, a4.y, a4.z, a4.w};
            const float bbv[4] = {b4.x, b4.y, b4.z, b4.w};
#pragma unroll
            for (int i = 0; i < 4; ++i)
#pragma unroll
                for (int j = 0; j < 4; ++j)
                    acc[i][j] = fmaf(aa[i], bbv[j], acc[i][j]);
        }
        __syncthreads();
    }
    const float* rnb = rn + (size_t)bm * LM1 + t0;
    float* Gout = G + ((size_t)bm * NBLK + blk) * (TBLK * TBLK);
#pragma unroll
    for (int i = 0; i < 4; ++i) {
        const int t = (ty << 2) + i;
        const float rt = (t < Tb) ? rnb[t] : 0.f;
#pragma unroll
        for (int j = 0; j < 4; ++j) {
            const int s = (tx << 2) + j;
            const int d = s - t;
            if (d >= 0) {
                const float val = (t < Tb && s < Tb) ? rt * rnb[s] * acc[i][j] : 0.f;
                Gout[(size_t)t * TBLK + d] = val;
            }
        }
    }
}

// one chunk of the pending-shift chain: p_{d0-1..d0+2} updated with G[d0..d0+3]
#define CH4(g,pA,pB,pC,pD,pE) \
    pA = fmaf(g.x, vv, pB); pB = fmaf(g.y, vv, pC); \
    pC = fmaf(g.z, vv, pD); pD = fmaf(g.w, vv, pE);

// ---------------------------------------------------------------------------
// Fused scan, 256 WGs x 1024 threads, 1 WG/CU, VGPR cap 128.
// Phase B pending state = 64 NAMED scalar registers (p00..p63): rounds 2-4
// proved the compiler sends float p[64] arrays to scratch regardless of
// launch bounds (VGPR_Count 108/64 + latency-bound 8.8-13.3 ms).
// ---------------------------------------------------------------------------
__global__ void __launch_bounds__(1024, 1) k_scan(
    const float* __restrict__ K, const float* __restrict__ rn,
    const float* __restrict__ nk2, const float* __restrict__ G,
    float* __restrict__ Mm, float* __restrict__ Vext, float* __restrict__ AU,
    float omA)
{
    cg::grid_group grid = cg::this_grid();
    const int wg  = blockIdx.x;
    const int tid = threadIdx.x;
    __shared__ float sh[8704];
    __shared__ float part[32];

    // zero M
    {
        float4* M4 = (float4*)Mm;
        for (int i = wg * 1024 + tid; i < (B_*2*H_*H_) / 4; i += NWG * 1024)
            M4[i] = make_float4(0.f, 0.f, 0.f, 0.f);
    }
    grid.sync();

    for (int blk = 0; blk < NBLK; ++blk) {
        const int t0 = blk * TBLK;
        const int Tb = (LM1 - t0 < TBLK) ? (LM1 - t0) : TBLK;

        // ---- Phase A : Vext = rn ⊙ (K_blk @ M^T);  512 active thr, K-split ----
        {
            const int sub = tid >> 8, t256 = tid & 255;
            const bool act = sub < 2;
            float* As = sh + sub * 2176;
            float* Bs = As + 1088;
            float* Cred = sh + 4352;
            const int bm = wg >> 3, n0 = (wg & 7) << 6;
            const int b = bm >> 1, m = bm & 1;
            const int tx = t256 & 15, ty = t256 >> 4;
            const int lr = t256 >> 2, lk4 = (t256 & 3) << 2;
            const float* Abase = K + ((size_t)(b * LM1 + t0)) * D_ + m * H_ + (act ? sub * 256 : 0);
            const float* Bbase = Mm + (size_t)bm * H_ * H_ + (act ? sub * 256 : 0);
            float acc[4][4];
#pragma unroll
            for (int i = 0; i < 4; ++i)
#pragma unroll
                for (int j = 0; j < 4; ++j) acc[i][j] = 0.f;

            for (int kk = 0; kk < 256; kk += 16) {
                if (act) {
                    const float4 av = (lr < Tb) ? *(const float4*)(Abase + (size_t)lr * D_ + kk + lk4)
                                                : make_float4(0.f,0.f,0.f,0.f);
                    const float4 bv = *(const float4*)(Bbase + (size_t)(n0 + lr) * H_ + kk + lk4);
                    As[(lk4+0)*68 + lr] = av.x; As[(lk4+1)*68 + lr] = av.y;
                    As[(lk4+2)*68 + lr] = av.z; As[(lk4+3)*68 + lr] = av.w;
                    Bs[(lk4+0)*68 + lr] = bv.x; Bs[(lk4+1)*68 + lr] = bv.y;
                    Bs[(lk4+2)*68 + lr] = bv.z; Bs[(lk4+3)*68 + lr] = bv.w;
                }
                __syncthreads();
                if (act) {
#pragma unroll
                    for (int k = 0; k < 16; ++k) {
                        const float4 a4 = *(const float4*)&As[k*68 + (ty << 2)];
                        const float4 b4 = *(const float4*)&Bs[k*68 + (tx << 2)];
                        const float aa[4] = {a4.x, a4.y, a4.z, a4.w};
                        const float bbv[4] = {b4.x, b4.y, b4.z, b4.w};
#pragma unroll
                        for (int i = 0; i < 4; ++i)
#pragma unroll
                            for (int j = 0; j < 4; ++j)
                                acc[i][j] = fmaf(aa[i], bbv[j], acc[i][j]);
                    }
                }
                __syncthreads();
            }
            if (sub == 1) {
#pragma unroll
                for (int i = 0; i < 4; ++i)
#pragma unroll
                    for (int j = 0; j < 4; ++j)
                        Cred[((size_t)((ty << 2) + i) << 6) + (tx << 2) + j] = acc[i][j];
            }
            __syncthreads();
            if (sub == 0) {
                const float* rnb = rn + (size_t)bm * LM1 + t0;
#pragma unroll
                for (int i = 0; i < 4; ++i) {
                    const int t = (ty << 2) + i;
                    if (t < Tb) {
                        const float rv = rnb[t];
                        const float* cr = &Cred[((size_t)t << 6) + (tx << 2)];
                        *(float4*)(Vext + ((size_t)bm * TBLK + t) * H_ + n0 + (tx << 2)) =
                            make_float4(rv*(acc[i][0]+cr[0]), rv*(acc[i][1]+cr[1]),
                                        rv*(acc[i][2]+cr[2]), rv*(acc[i][3]+cr[3]));
                    }
                }
            }
        }
        grid.sync();

        // ---- Phase B (seq): 16 WGs, thread = (m = tid>>9, j = tid&511) ----
        if (wg < B_) {
            const int b = wg;
            const int m = tid >> 9;
            const int wid = tid >> 6, lane = tid & 63;
            {
                const float4* s0 = (const float4*)(G + ((size_t)(b*2+0) * NBLK + blk) * (TBLK*TBLK));
                const float4* s1 = (const float4*)(G + ((size_t)(b*2+1) * NBLK + blk) * (TBLK*TBLK));
                float4* dst = (float4*)sh;
                dst[tid]        = s0[tid];
                dst[tid + 1024] = s1[tid];
            }
            float p00=0.f,p01=0.f,p02=0.f,p03=0.f,p04=0.f,p05=0.f,p06=0.f,p07=0.f;
            float p08=0.f,p09=0.f,p10=0.f,p11=0.f,p12=0.f,p13=0.f,p14=0.f,p15=0.f;
            float p16=0.f,p17=0.f,p18=0.f,p19=0.f,p20=0.f,p21=0.f,p22=0.f,p23=0.f;
            float p24=0.f,p25=0.f,p26=0.f,p27=0.f,p28=0.f,p29=0.f,p30=0.f,p31=0.f;
            float p32=0.f,p33=0.f,p34=0.f,p35=0.f,p36=0.f,p37=0.f,p38=0.f,p39=0.f;
            float p40=0.f,p41=0.f,p42=0.f,p43=0.f,p44=0.f,p45=0.f,p46=0.f,p47=0.f;
            float p48=0.f,p49=0.f,p50=0.f,p51=0.f,p52=0.f,p53=0.f,p54=0.f,p55=0.f;
            float p56=0.f,p57=0.f,p58=0.f,p59=0.f,p60=0.f,p61=0.f,p62=0.f,p63=0.f;
            __syncthreads();

            const float* Kb  = K + ((size_t)(b * LM1 + t0)) * D_ + tid;     // m*H_+j == tid
            const float* Vb  = Vext + ((size_t)(b*2+m) * TBLK) * H_ + (tid & 511);
            float* AUp       = AU   + ((size_t)(b*2+m) * TBLK) * H_ + (tid & 511);
            const float* qs  = nk2 + (size_t)(b*2+0) * LM1 + t0;
            const float* qe  = nk2 + (size_t)(b*2+1) * LM1 + t0;
            const float* Gm  = sh + (m << 12);

            float kc = Kb[0], vc = Vb[0];
            float ncs = qs[0], nce = qe[0];

            for (int t = 0; t < Tb; ++t) {
                const float u = kc - vc - p00;
                float kn = 0.f, vn = 0.f, nns = 0.f, nne = 0.f;
                if (t + 1 < Tb) {
                    kn  = Kb[(size_t)(t+1) * D_];
                    vn  = Vb[(t+1) * H_];
                    nns = qs[t+1];
                    nne = qe[t+1];
                }
                float s = u * u;
#pragma unroll
                for (int o = 32; o; o >>= 1) s += __shfl_xor(s, o);
                float* pp = &part[(t & 1) << 4];
                if (lane == 0) pp[wid] = s;
                __syncthreads();
                float Ns = 0.f, Ne = 0.f;
#pragma unroll
                for (int i = 0; i < 8; ++i) { Ns += pp[i]; Ne += pp[i + 8]; }
                const bool fire = (Ns >= 0.49f * ncs) || (Ne >= 0.49f * nce);
                const float w = (float)(t0 + t + 1) * (1.0f / (float)L_);
                const float scale = m ? (omA * w) : omA;
                const float vv = fire ? scale * u : 0.f;   // vv==0 -> chain is exact shift
                AUp[(size_t)t * H_] = vv;

                const float4* Gr = (const float4*)(Gm + (t << 6));
                float4 gA = Gr[0], gB = Gr[1];
                p00 = fmaf(gA.y, vv, p01); p01 = fmaf(gA.z, vv, p02); p02 = fmaf(gA.w, vv, p03);
                gA = Gr[2];
                CH4(gB, p03,p04,p05,p06,p07)  gB = Gr[3];
                CH4(gA, p07,p08,p09,p10,p11)  gA = Gr[4];
                CH4(gB, p11,p12,p13,p14,p15)  gB = Gr[5];
                CH4(gA, p15,p16,p17,p18,p19)  gA = Gr[6];
                CH4(gB, p19,p20,p21,p22,p23)  gB = Gr[7];
                CH4(gA, p23,p24,p25,p26,p27)  gA = Gr[8];
                CH4(gB, p27,p28,p29,p30,p31)  gB = Gr[9];
                CH4(gA, p31,p32,p33,p34,p35)  gA = Gr[10];
                CH4(gB, p35,p36,p37,p38,p39)  gB = Gr[11];
                CH4(gA, p39,p40,p41,p42,p43)  gA = Gr[12];
                CH4(gB, p43,p44,p45,p46,p47)  gB = Gr[13];
                CH4(gA, p47,p48,p49,p50,p51)  gA = Gr[14];
                CH4(gB, p51,p52,p53,p54,p55)  gB = Gr[15];
                CH4(gA, p55,p56,p57,p58,p59)
                CH4(gB, p59,p60,p61,p62,p63)
                p63 = 0.f;

                kc = kn; vc = vn; ncs = nns; nce = nne;
            }
        }
        grid.sync();

        // ---- Phase C : M += (a∘U)^T @ (rn ⊙ K_blk); 4 teams x 2 rounds ----
        {
            const int sub = tid >> 8, t256 = tid & 255;
            float* As = sh + sub * 2176;
            float* Bs = As + 1088;
            const int tx = t256 & 15, ty = t256 >> 4;
            const int lk = t256 >> 4, lc4 = (t256 & 15) << 2;
#pragma unroll
            for (int rq = 0; rq < 2; ++rq) {
                const int task = rq * 1024 + wg * 4 + sub;    // 0..2047
                const int bm = task >> 6;
                const int i0 = ((task >> 3) & 7) << 6;
                const int j0 = (task & 7) << 6;
                const int b = bm >> 1, m = bm & 1;
                float acc[4][4];
#pragma unroll
                for (int i = 0; i < 4; ++i)
#pragma unroll
                    for (int j = 0; j < 4; ++j) acc[i][j] = 0.f;

                for (int kk = 0; kk < TBLK; kk += 16) {
                    const int kt = kk + lk;
                    const bool ok = kt < Tb;
                    float4 av = ok ? *(const float4*)(AU + ((size_t)bm * TBLK + kt) * H_ + i0 + lc4)
                                   : make_float4(0.f,0.f,0.f,0.f);
                    const float rv = ok ? rn[(size_t)bm * LM1 + t0 + kt] : 0.f;
                    float4 bv = ok ? *(const float4*)(K + ((size_t)(b * LM1 + t0 + kt)) * D_ + m * H_ + j0 + lc4)
                                   : make_float4(0.f,0.f,0.f,0.f);
                    bv.x *= rv; bv.y *= rv; bv.z *= rv; bv.w *= rv;
                    *(float4*)&As[lk*68 + lc4] = av;
                    *(float4*)&Bs[lk*68 + lc4] = bv;
                    __syncthreads();
#pragma unroll
                    for (int k = 0; k < 16; ++k) {
                        const float4 a4 = *(const float4*)&As[k*68 + (ty << 2)];
                        const float4 b4 = *(const float4*)&Bs[k*68 + (tx << 2)];
                        const float aa[4] = {a4.x, a4.y, a4.z, a4.w};
                        const float bbv[4] = {b4.x, b4.y, b4.z, b4.w};
#pragma unroll
                        for (int i = 0; i < 4; ++i)
#pragma unroll
                            for (int j = 0; j < 4; ++j)
                                acc[i][j] = fmaf(aa[i], bbv[j], acc[i][j]);
                    }
                    __syncthreads();
                }
#pragma unroll
                for (int i = 0; i < 4; ++i) {
                    float4* pt = (float4*)(Mm + ((size_t)bm * H_ + i0 + (ty << 2) + i) * H_ + j0 + (tx << 2));
                    float4 old = *pt;
                    old.x += acc[i][0]; old.y += acc[i][1]; old.z += acc[i][2]; old.w += acc[i][3];
                    *pt = old;
                }
            }
        }
        grid.sync();
    }
}

// ---------------------------------------------------------------------------
// query path: qn (normalized projections) + gnull.  grid B_, block 1024
// ---------------------------------------------------------------------------
__global__ void __launch_bounds__(1024) k_q(
    const float* __restrict__ x, const float* __restrict__ Wsem,
    const float* __restrict__ Wepi, const float* __restrict__ nw,
    const float* __restrict__ nb, float* __restrict__ qn, float* __restrict__ gnull)
{
    const int b = blockIdx.x, tid = threadIdx.x;
    __shared__ float qsh[D_];
    __shared__ float red[16];
    qsh[tid] = x[((size_t)b * L_ + (L_ - 1)) * D_ + tid];
    __syncthreads();
    const float* wrow = (tid < H_) ? (Wsem + (size_t)tid * D_)
                                   : (Wepi + (size_t)(tid - H_) * D_);
    float s = 0.f;
    for (int d = 0; d < D_; d += 4) {
        const float4 w4 = *(const float4*)(wrow + d);
        s += qsh[d]*w4.x + qsh[d+1]*w4.y + qsh[d+2]*w4.z + qsh[d+3]*w4.w;
    }
    float sq = s * s;
#pragma unroll
    for (int o = 32; o; o >>= 1) sq += __shfl_xor(sq, o);
    const int wid = tid >> 6, lane = tid & 63;
    if (lane == 0) red[wid] = sq;
    __syncthreads();
    float n2s = 0.f, n2e = 0.f;
#pragma unroll
    for (int i = 0; i < 8; ++i) { n2s += red[i]; n2e += red[i + 8]; }
    const float rns = 1.f / fmaxf(sqrtf(n2s), 1e-12f);
    const float rne = 1.f / fmaxf(sqrtf(n2e), 1e-12f);
    qn[(size_t)b * D_ + tid] = s * ((tid < H_) ? rns : rne);
    if (wid == 0) {
        float g = 0.f;
        for (int d = lane * 4; d < D_; d += 256) {
            const float4 w4 = *(const float4*)(nw + d);
            g += qsh[d]*w4.x + qsh[d+1]*w4.y + qsh[d+2]*w4.z + qsh[d+3]*w4.w;
        }
#pragma unroll
        for (int o = 32; o; o >>= 1) g += __shfl_xor(g, o);
        if (lane == 0) gnull[b] = 1.f / (1.f + expf(-(g + nb[0])));
    }
}

// ---------------------------------------------------------------------------
// rg[b][n] = gnull[b] * sum_j M[b][m][i][j] qn[b][m*512+j]   grid (16,256), block 256
// ---------------------------------------------------------------------------
__global__ void k_rmv(const float* __restrict__ M, const float* __restrict__ qn,
                      const float* __restrict__ gnull, float* __restrict__ rg)
{
    const int b = blockIdx.x;
    const int n = blockIdx.y * 4 + (threadIdx.x >> 6);
    const int lane = threadIdx.x & 63;
    const int m = n >> 9, i = n & 511;
    const float* Mr = M + ((size_t)(b*2+m) * H_ + i) * H_;
    const float* qv = qn + (size_t)b * D_ + m * H_;
    float s = 0.f;
#pragma unroll
    for (int it = 0; it < 2; ++it) {
        const int j = lane * 4 + it * 256;
        const float4 m4 = *(const float4*)(Mr + j);
        const float4 q4 = *(const float4*)(qv + j);
        s += m4.x*q4.x + m4.y*q4.y + m4.z*q4.z + m4.w*q4.w;
    }
#pragma unroll
    for (int o = 32; o; o >>= 1) s += __shfl_xor(s, o);
    if (lane == 0) rg[(size_t)b * D_ + n] = gnull[b] * s;
}

// ---------------------------------------------------------------------------
// out[b][o] = sum_d rg[b][d] * outw[o][d] + outb[o]        grid (16,256), block 256
// ---------------------------------------------------------------------------
__global__ void k_out(const float* __restrict__ rg, const float* __restrict__ outw,
                      const float* __restrict__ outb, float* __restrict__ out)
{
    const int b = blockIdx.x;
    const int o = blockIdx.y * 4 + (threadIdx.x >> 6);
    const int lane = threadIdx.x & 63;
    const float* wr = outw + (size_t)o * D_;
    const float* rv = rg + (size_t)b * D_;
    float s = 0.f;
#pragma unroll
    for (int it = 0; it < 4; ++it) {
        const int j = lane * 4 + it * 256;
        const float4 w4 = *(const float4*)(wr + j);
        const float4 r4 = *(const float4*)(rv + j);
        s += w4.x*r4.x + w4.y*r4.y + w4.z*r4.z + w4.w*r4.w;
    }
#pragma unroll
    for (int o2 = 32; o2; o2 >>= 1) s += __shfl_xor(s, o2);
    if (lane == 0) out[(size_t)b * D_ + o] = s + outb[o];
}

// ---------------------------------------------------------------------------
extern "C" void kernel_launch(void* const* d_in, const int* in_sizes, int n_in,
                              void* d_out, int out_size, void* d_ws, size_t ws_size,
                              hipStream_t stream)
{
    (void)in_sizes; (void)n_in; (void)out_size;
    const float* x     = (const float*)d_in[0];
    const float* Wsem  = (const float*)d_in[1];
    const float* Wepi  = (const float*)d_in[2];
    const float* nullw = (const float*)d_in[3];
    const float* nullb = (const float*)d_in[4];
    const float* outw  = (const float*)d_in[5];
    const float* outb  = (const float*)d_in[6];
    float* out = (float*)d_out;

    float* ws = (float*)d_ws;
    size_t off = 0;
    float* K     = ws + off; off += (size_t)B_ * LM1 * D_;
    float* nk2   = ws + off; off += (size_t)B_ * 2 * LM1;
    float* rn    = ws + off; off += (size_t)B_ * 2 * LM1;
    float* Mm    = ws + off; off += (size_t)B_ * 2 * H_ * H_;
    float* Vext  = ws + off; off += (size_t)B_ * 2 * TBLK * H_;
    float* G     = ws + off; off += (size_t)B_ * 2 * NBLK * TBLK * TBLK;
    float* AU    = ws + off; off += (size_t)B_ * 2 * TBLK * H_;
    float* qn    = ws + off; off += (size_t)B_ * D_;
    float* gnull = ws + off; off += (size_t)B_;
    float* rg    = ws + off; off += (size_t)B_ * D_;
    if (ws_size < off * sizeof(float)) return;   // insufficient scratch -> fail loudly

    float omA = (float)(1.0 - pow(0.95, 96.0 / 2048.0));

    k_proj <<<dim3(512, 16), 256, 0, stream>>>(x, Wsem, Wepi, K);
    k_norms<<<dim3(B_ * LM1), 256, 0, stream>>>(K, nk2, rn);
    k_gram <<<dim3(NBLK, B_ * 2), 256, 0, stream>>>(K, rn, G);

    {
        void* args[] = { (void*)&K, (void*)&rn, (void*)&nk2, (void*)&G,
                         (void*)&Mm, (void*)&Vext, (void*)&AU, (void*)&omA };
        hipLaunchCooperativeKernel((void*)k_scan, dim3(NWG), dim3(1024), args, 0, stream);
    }

    k_q  <<<dim3(B_), 1024, 0, stream>>>(x, Wsem, Wepi, nullw, nullb, qn, gnull);
    k_rmv<<<dim3(16, 256), 256, 0, stream>>>(Mm, qn, gnull, rg);
    k_out<<<dim3(16, 256), 256, 0, stream>>>(rg, outw, outb, out);
}